// Round 4
// baseline (146.839 us; speedup 1.0000x reference)
//
#include <hip/hip_runtime.h>
#include <math.h>

// Tropical (max-plus) depthwise conv2d, 5x5, stride 1, pad 2, dilation 1.
// x: (8,32,224,224) f32, kernel: (32,1,5,5) f32, out: (8,32,224,224) f32.
// out[b,c,h,w] = max_{i,j} x[b,c,h-2+i, w-2+j] + kernel[c,0,4-i,4-j]
//
// R4: persistent quarter-image blocks, 4 tiles of 16 rows each, with
// register-staged prefetch: next tile's global loads are issued right after
// the ready-barrier and fly during the current tile's compute. Fixes the
// load->barrier->compute serialization of R3.

#define TC_B 8
#define TC_C 32
#define TC_H 224
#define TC_W 224
#define TC_WQ 56          // float4 per row
#define T_STRIDE 232      // floats per tile row: 1 halo f4 | 56 data f4 | 1 halo f4
#define T_ROWS 20         // 16 data rows + 2 halo top + 2 halo bottom
#define N_TILES 4
#define QROWS 56          // output rows per block (quarter image)

__global__ __launch_bounds__(512) void tropical_conv2d_kernel(
    const float* __restrict__ x, const float* __restrict__ kern,
    float* __restrict__ out) {
  const int tt = threadIdx.x;        // 0..511
  const int wq = tt & 63;            // lane within wave
  const int yl = tt >> 6;            // wave id 0..7
  const int blk = blockIdx.x;
  const int hq = blk & 3;            // quarter index
  const int bc = blk >> 2;           // b*C + c (wave-uniform)
  const int c = bc & (TC_C - 1);
  const int h0 = hq * QROWS;

  __shared__ float tile[T_ROWS * T_STRIDE];   // 18,560 B

  const float NEG = -INFINITY;
  const float4 NINF4 = make_float4(NEG, NEG, NEG, NEG);

  // one-time -inf fill of halo column f4s (index 0 and 57 of each row);
  // staging never writes them, so this persists across tiles.
  if (tt < 2 * T_ROWS) {
    const int r = (tt >= T_ROWS) ? tt - T_ROWS : tt;
    const int cf = (tt >= T_ROWS) ? 57 : 0;
    *(float4*)&tile[r * T_STRIDE + cf * 4] = NINF4;
  }

  // flipped weights; c is uniform -> scalar loads
  float w[25];
  #pragma unroll
  for (int q = 0; q < 25; ++q) w[q] = kern[c * 25 + 24 - q];

  const float* xp = x + (size_t)bc * (TC_H * TC_W);
  float* op = out + (size_t)bc * (TC_H * TC_W);

  // staging slot assignment: flat f4 index f = tt + 512k over 20x56 tile
  int sr[3], sc[3];
  bool sv[3];
  #pragma unroll
  for (int k = 0; k < 3; ++k) {
    const int f = tt + k * 512;
    sv[k] = f < T_ROWS * TC_WQ;      // < 1120
    sr[k] = f / TC_WQ;
    sc[k] = f % TC_WQ;
  }

  // preload tile 0 into registers
  float4 reg[3];
  #pragma unroll
  for (int k = 0; k < 3; ++k) {
    const int ir = h0 - 2 + sr[k];
    reg[k] = (sv[k] && ir >= 0 && ir < TC_H)
                 ? ((const float4*)(xp + (size_t)ir * TC_W))[sc[k]]
                 : NINF4;
  }

  for (int t = 0; t < N_TILES; ++t) {
    // commit staged registers to LDS (data cols at f4 index 1..56)
    #pragma unroll
    for (int k = 0; k < 3; ++k)
      if (sv[k]) *(float4*)&tile[sr[k] * T_STRIDE + 4 + 4 * sc[k]] = reg[k];
    __syncthreads();

    // issue next tile's global loads NOW; they fly during compute below
    if (t + 1 < N_TILES) {
      const int g0 = h0 + 16 * (t + 1) - 2;
      #pragma unroll
      for (int k = 0; k < 3; ++k) {
        const int ir = g0 + sr[k];
        reg[k] = (sv[k] && ir >= 0 && ir < TC_H)
                     ? ((const float4*)(xp + (size_t)ir * TC_W))[sc[k]]
                     : NINF4;
      }
    }

    // compute: wave yl owns output rows tr0, tr0+1 of this tile
    const int nrows = (t < N_TILES - 1) ? 16 : 8;   // last tile is 8 rows
    const int tr0 = 2 * yl;
    if (wq < TC_WQ && tr0 < nrows) {
      float acc[2][4];
      #pragma unroll
      for (int o = 0; o < 2; ++o)
        #pragma unroll
        for (int k = 0; k < 4; ++k) acc[o][k] = NEG;

      // tile row j holds input row (h0 + 16t - 2 + j)
      // output row tr0+o uses tile rows tr0+o .. tr0+o+4  -> jr in [0,6)
      #pragma unroll
      for (int jr = 0; jr < 6; ++jr) {
        const float* rp = &tile[(tr0 + jr) * T_STRIDE + 4 * wq];
        const float4 A = *(const float4*)(rp);
        const float4 Bv = *(const float4*)(rp + 4);
        const float4 Cv = *(const float4*)(rp + 8);
        float v[12] = {A.x, A.y, A.z, A.w, Bv.x, Bv.y, Bv.z, Bv.w,
                       Cv.x, Cv.y, Cv.z, Cv.w};
        #pragma unroll
        for (int o = 0; o < 2; ++o) {
          const int i = jr - o;                 // weight row, compile-time
          if (i < 0 || i > 4) continue;
          #pragma unroll
          for (int k = 0; k < 4; ++k) {
            const float t0 = v[2 + k] + w[i * 5 + 0];
            const float t1 = v[3 + k] + w[i * 5 + 1];
            const float t2 = v[4 + k] + w[i * 5 + 2];
            const float t3 = v[5 + k] + w[i * 5 + 3];
            const float t4 = v[6 + k] + w[i * 5 + 4];
            acc[o][k] = fmaxf(fmaxf(fmaxf(acc[o][k], t0), t1),
                              fmaxf(fmaxf(t2, t3), t4));
          }
        }
      }

      const int h = h0 + 16 * t + tr0;
      ((float4*)(op + (size_t)h * TC_W))[wq] =
          make_float4(acc[0][0], acc[0][1], acc[0][2], acc[0][3]);
      ((float4*)(op + (size_t)(h + 1) * TC_W))[wq] =
          make_float4(acc[1][0], acc[1][1], acc[1][2], acc[1][3]);
    }
    __syncthreads();   // all reads of tile done before next ds_write
  }
}

extern "C" void kernel_launch(void* const* d_in, const int* in_sizes, int n_in,
                              void* d_out, int out_size, void* d_ws, size_t ws_size,
                              hipStream_t stream) {
  const float* x = (const float*)d_in[0];
  const float* k = (const float*)d_in[1];
  float* out = (float*)d_out;

  dim3 block(512, 1, 1);
  dim3 grid(TC_B * TC_C * 4, 1, 1);
  tropical_conv2d_kernel<<<grid, block, 0, stream>>>(x, k, out);
}

// Round 5
// 118.760 us; speedup vs baseline: 1.2364x; 1.2364x over previous
//
#include <hip/hip_runtime.h>
#include <math.h>

// Tropical (max-plus) depthwise conv2d, 5x5, stride 1, pad 2, dilation 1.
// x: (8,32,224,224) f32, kernel: (32,1,5,5) f32, out: (8,32,224,224) f32.
// out[b,c,h,w] = max_{i,j} x[b,c,h-2+i, w-2+j] + kernel[c,0,4-i,4-j]
//
// R5: pure-register, branch-free. All 24 float4 loads per thread issued as
// one unconditional batch (addresses clamped in-bounds), OOB lanes/rows
// patched to -inf with cndmask AFTER the loads. No LDS, no barriers, no
// control flow between loads -> compiler can keep them all in flight.
// (R1/R2 had VGPR=12: branches between loads serialized them.)

#define TC_B 8
#define TC_C 32
#define TC_H 224
#define TC_W 224
#define TC_WQ 56     // float4 per row
#define TC_HG 14     // 224 / 16 rows per block

__device__ __forceinline__ float4 sel4(bool ok, float4 v, float n) {
  return make_float4(ok ? v.x : n, ok ? v.y : n, ok ? v.z : n, ok ? v.w : n);
}

__global__ __launch_bounds__(256) void tropical_conv2d_kernel(
    const float* __restrict__ x, const float* __restrict__ kern,
    float* __restrict__ out) {
  const int tid = threadIdx.x;
  const int wq = tid & 63;       // lane: float4 column, active < 56
  const int yl = tid >> 6;       // wave 0..3 within block
  const int blk = blockIdx.x;
  const int hg = blk % TC_HG;
  const int bc = blk / TC_HG;    // b*C + c (uniform)
  const int c = bc & (TC_C - 1);

  if (wq >= TC_WQ) return;       // 8 idle lanes per wave (exec-masked)

  const int hbase = hg * 16 + yl * 4;   // first of 4 output rows
  const float* xp = x + (size_t)bc * (TC_H * TC_W);
  const float NEG = -INFINITY;

  // clamped column neighbors (always-valid addresses)
  const int wqm1 = (wq > 0) ? wq - 1 : 0;
  const int wqp1 = (wq < TC_WQ - 1) ? wq + 1 : TC_WQ - 1;
  const bool lok = (wq > 0);
  const bool rok = (wq < TC_WQ - 1);

  // ---- one unconditional load batch: 8 rows x 3 float4 ----
  float4 rA[8], rB[8], rC[8];
  #pragma unroll
  for (int i = 0; i < 8; ++i) {
    const int rr = hbase - 2 + i;
    const int rc = rr < 0 ? 0 : (rr > TC_H - 1 ? TC_H - 1 : rr);
    const float4* row = (const float4*)(xp + (size_t)rc * TC_W);
    rA[i] = row[wqm1];
    rB[i] = row[wq];
    rC[i] = row[wqp1];
  }

  // weights: uniform address -> scalar loads, overlap with vmem latency
  // w[i*5+j] = wflip[i][j] = kern[c][4-i][4-j]
  float w[25];
  #pragma unroll
  for (int q = 0; q < 25; ++q) w[q] = kern[c * 25 + 24 - q];

  // ---- branch-free OOB fixups (cndmask, after loads are in flight) ----
  #pragma unroll
  for (int i = 0; i < 8; ++i) {
    const int rr = hbase - 2 + i;
    const bool rowok = (rr >= 0) && (rr < TC_H);
    rA[i] = sel4(rowok && lok, rA[i], NEG);
    rB[i] = sel4(rowok, rB[i], NEG);
    rC[i] = sel4(rowok && rok, rC[i], NEG);
  }

  // ---- compute: 4 output rows x 4 cols ----
  float acc[4][4];
  #pragma unroll
  for (int o = 0; o < 4; ++o)
    #pragma unroll
    for (int k = 0; k < 4; ++k) acc[o][k] = NEG;

  #pragma unroll
  for (int ri = 0; ri < 8; ++ri) {
    // v[m] = x col 4*wq - 4 + m at row hbase-2+ri
    const float v[12] = {rA[ri].x, rA[ri].y, rA[ri].z, rA[ri].w,
                         rB[ri].x, rB[ri].y, rB[ri].z, rB[ri].w,
                         rC[ri].x, rC[ri].y, rC[ri].z, rC[ri].w};
    #pragma unroll
    for (int o = 0; o < 4; ++o) {
      const int i = ri - o;              // weight row (compile-time)
      if (i < 0 || i > 4) continue;
      #pragma unroll
      for (int k = 0; k < 4; ++k) {
        const float t0 = v[2 + k] + w[i * 5 + 0];
        const float t1 = v[3 + k] + w[i * 5 + 1];
        const float t2 = v[4 + k] + w[i * 5 + 2];
        const float t3 = v[5 + k] + w[i * 5 + 3];
        const float t4 = v[6 + k] + w[i * 5 + 4];
        // 6-way max: 2x v_max3 + 1x v_max
        acc[o][k] = fmaxf(fmaxf(fmaxf(acc[o][k], t0), t1),
                          fmaxf(fmaxf(t2, t3), t4));
      }
    }
  }

  float* op = out + (size_t)bc * (TC_H * TC_W) + (size_t)hbase * TC_W;
  #pragma unroll
  for (int o = 0; o < 4; ++o) {
    ((float4*)(op + (size_t)o * TC_W))[wq] =
        make_float4(acc[o][0], acc[o][1], acc[o][2], acc[o][3]);
  }
}

extern "C" void kernel_launch(void* const* d_in, const int* in_sizes, int n_in,
                              void* d_out, int out_size, void* d_ws, size_t ws_size,
                              hipStream_t stream) {
  const float* x = (const float*)d_in[0];
  const float* k = (const float*)d_in[1];
  float* out = (float*)d_out;

  dim3 block(256, 1, 1);
  dim3 grid(TC_B * TC_C * TC_HG, 1, 1);
  tropical_conv2d_kernel<<<grid, block, 0, stream>>>(x, k, out);
}

// Round 6
// 108.808 us; speedup vs baseline: 1.3495x; 1.0915x over previous
//
#include <hip/hip_runtime.h>
#include <math.h>

// Tropical (max-plus) depthwise conv2d, 5x5, stride 1, pad 2, dilation 1.
// x: (8,32,224,224) f32, kernel: (32,1,5,5) f32, out: (8,32,224,224) f32.
// out[b,c,h,w] = max_{i,j} x[b,c,h-2+i, w-2+j] + kernel[c,0,4-i,4-j]
//
// R6: async global->LDS staging via __builtin_amdgcn_global_load_lds (16B).
// No VGPR round-trip for staging (R3/R5 were serialized by register
// pressure), so all 20 row-loads are in flight at once; one barrier drain,
// hidden by ~7 blocks/CU occupancy. LDS row = [1 f4 -inf halo][56 data f4]
// [8 f4 lane-spill], stride 65 f4; right-edge garbage patched by cndmask.

#define TC_B 8
#define TC_C 32
#define TC_H 224
#define TC_W 224
#define TC_WQ 56          // f4 per image row
#define TC_HG 14          // 224/16 row-groups
#define T_ROWS 20         // 16 data + 2+2 halo rows
#define ROW_F4 65         // LDS row stride in float4
#define ROW_FL (ROW_F4 * 4)

__global__ __launch_bounds__(256) void tropical_conv2d_kernel(
    const float* __restrict__ x, const float* __restrict__ kern,
    float* __restrict__ out) {
  const int tid = threadIdx.x;
  const int lane = tid & 63;
  const int yl = tid >> 6;          // wave 0..3
  const int blk = blockIdx.x;
  const int hg = blk % TC_HG;
  const int bc = blk / TC_HG;       // b*C + c (uniform)
  const int c = bc & (TC_C - 1);

  __shared__ float tile[T_ROWS * ROW_FL];   // 20*65*16 = 20800 B

  const float NEG = -INFINITY;
  const float4 NINF4 = make_float4(NEG, NEG, NEG, NEG);
  const float* xp = x + (size_t)bc * (TC_H * TC_W);

  // left-halo f4 (index 0) of every row = -inf; staging never writes f4 0.
  if (tid < T_ROWS) *(float4*)&tile[tid * ROW_FL] = NINF4;

  // ---- staging: wave yl owns tile rows yl*5 .. yl*5+4 ----
  const int cl = lane < TC_WQ ? lane : TC_WQ - 1;   // clamp spill lanes
  #pragma unroll
  for (int rr = 0; rr < 5; ++rr) {
    const int r = yl * 5 + rr;                      // wave-uniform
    const int g = hg * 16 - 2 + r;                  // global row, uniform
    float* ldsrow = &tile[r * ROW_FL + 4];          // f4 index 1 (uniform base)
    if (g >= 0 && g < TC_H) {
      const float* gp = xp + (size_t)g * TC_W + cl * 4;
      // lane i -> LDS f4 index 1+i, holding x f4 col min(i,55)
      __builtin_amdgcn_global_load_lds(
          (const __attribute__((address_space(1))) void*)gp,
          (__attribute__((address_space(3))) void*)ldsrow, 16, 0, 0);
    } else {
      *(float4*)(ldsrow + (size_t)lane * 4) = NINF4;  // OOB row = -inf
    }
  }

  // weights while staging flies: c uniform -> scalar loads
  // w[i*5+j] = wflip[i][j] = kern[c][4-i][4-j]
  float w[25];
  #pragma unroll
  for (int q = 0; q < 25; ++q) w[q] = kern[c * 25 + 24 - q];

  __syncthreads();   // drains vmcnt (global_load_lds) + lgkmcnt

  if (lane >= TC_WQ) return;

  const int hbase = hg * 16 + yl * 4;   // first of this thread's 4 output rows

  float acc[4][4];
  #pragma unroll
  for (int o = 0; o < 4; ++o)
    #pragma unroll
    for (int k = 0; k < 4; ++k) acc[o][k] = NEG;

  const bool redge = (lane == TC_WQ - 1);

  // tile row (yl*4 + ri) holds input row hbase-2+ri
  #pragma unroll
  for (int ri = 0; ri < 8; ++ri) {
    const float* rp = &tile[(yl * 4 + ri) * ROW_FL + 4 * lane];
    const float4 A = *(const float4*)(rp);        // x cols 4l-4..4l-1 (or -inf halo)
    const float4 Bv = *(const float4*)(rp + 4);   // x cols 4l..4l+3
    const float4 Cv = *(const float4*)(rp + 8);   // x cols 4l+4..4l+7
    float v[12] = {A.x, A.y, A.z, A.w, Bv.x, Bv.y, Bv.z, Bv.w,
                   Cv.x, Cv.y, Cv.z, Cv.w};
    // right edge: f4 57 holds lane-spill garbage, taps use v[8],v[9] only
    v[8] = redge ? NEG : v[8];
    v[9] = redge ? NEG : v[9];

    #pragma unroll
    for (int o = 0; o < 4; ++o) {
      const int i = ri - o;                // weight row (compile-time)
      if (i < 0 || i > 4) continue;
      #pragma unroll
      for (int k = 0; k < 4; ++k) {
        const float t0 = v[2 + k] + w[i * 5 + 0];
        const float t1 = v[3 + k] + w[i * 5 + 1];
        const float t2 = v[4 + k] + w[i * 5 + 2];
        const float t3 = v[5 + k] + w[i * 5 + 3];
        const float t4 = v[6 + k] + w[i * 5 + 4];
        acc[o][k] = fmaxf(fmaxf(fmaxf(acc[o][k], t0), t1),
                          fmaxf(fmaxf(t2, t3), t4));
      }
    }
  }

  float* op = out + (size_t)bc * (TC_H * TC_W) + (size_t)hbase * TC_W;
  #pragma unroll
  for (int o = 0; o < 4; ++o) {
    ((float4*)(op + (size_t)o * TC_W))[lane] =
        make_float4(acc[o][0], acc[o][1], acc[o][2], acc[o][3]);
  }
}

extern "C" void kernel_launch(void* const* d_in, const int* in_sizes, int n_in,
                              void* d_out, int out_size, void* d_ws, size_t ws_size,
                              hipStream_t stream) {
  const float* x = (const float*)d_in[0];
  const float* k = (const float*)d_in[1];
  float* out = (float*)d_out;

  dim3 block(256, 1, 1);
  dim3 grid(TC_B * TC_C * TC_HG, 1, 1);
  tropical_conv2d_kernel<<<grid, block, 0, stream>>>(x, k, out);
}